// Round 10
// baseline (419.818 us; speedup 1.0000x reference)
//
#include <hip/hip_runtime.h>
#include <hip/hip_bf16.h>

typedef __attribute__((ext_vector_type(8))) short short8;
typedef __attribute__((ext_vector_type(4))) float f32x4;
typedef __attribute__((ext_vector_type(16))) float f32x16;
typedef unsigned short u16;
typedef unsigned int u32;

// B=2, T=2048, C=2048, H=16, HD=128; M = B*T = 4096, K = N = 2048
__device__ __forceinline__ u16 f2bf(float f){
  __hip_bfloat16 h = __float2bfloat16(f);
  return *reinterpret_cast<u16*>(&h);
}

__device__ __forceinline__ void gld16(const void* g, void* l){
  __builtin_amdgcn_global_load_lds((const __attribute__((address_space(1))) void*)g,
                                   (__attribute__((address_space(3))) void*)l, 16, 0, 0);
}

#define SCHED0() __builtin_amdgcn_sched_barrier(0)

// ---------------- f32 -> bf16 convert ----------------
__global__ __launch_bounds__(256) void cvt_kernel(const float* __restrict__ src,
                                                  u16* __restrict__ dst, int n){
  int i0 = (blockIdx.x*256 + threadIdx.x)*4;
  int stride = gridDim.x*256*4;
  for (int i = i0; i < n; i += stride){
    float4 f = *reinterpret_cast<const float4*>(src + i);
    ushort4 u;
    u.x = f2bf(f.x); u.y = f2bf(f.y); u.z = f2bf(f.z); u.w = f2bf(f.w);
    *reinterpret_cast<ushort4*>(dst + i) = u;
  }
}

// 4 weight matrices in one launch (blockIdx.y selects)
__global__ __launch_bounds__(256) void cvt4_kernel(
    const float* __restrict__ s0, const float* __restrict__ s1,
    const float* __restrict__ s2, const float* __restrict__ s3,
    u16* __restrict__ d0, u16* __restrict__ d1,
    u16* __restrict__ d2, u16* __restrict__ d3, int n){
  const float* s; u16* d;
  if (blockIdx.y == 0){ s = s0; d = d0; }
  else if (blockIdx.y == 1){ s = s1; d = d1; }
  else if (blockIdx.y == 2){ s = s2; d = d2; }
  else { s = s3; d = d3; }
  int i0 = (blockIdx.x*256 + threadIdx.x)*4;
  int stride = gridDim.x*256*4;
  for (int i = i0; i < n; i += stride){
    float4 f = *reinterpret_cast<const float4*>(s + i);
    ushort4 u;
    u.x = f2bf(f.x); u.y = f2bf(f.y); u.z = f2bf(f.z); u.w = f2bf(f.w);
    *reinterpret_cast<ushort4*>(d + i) = u;
  }
}

// ---------------- bf16 GEMM, 128x256 tile, BK=64, 8 waves (2Mx2Nx2K) -------
// (frozen from round 9 — K-split waves, tri-buffered LDS, counted vmcnt,
//  one barrier per K-tile, compiler-scheduled ds_read/MFMA interleave)
__device__ __forceinline__ void gemm256_body(const u16* __restrict__ A,
    const u16* __restrict__ W, void* __restrict__ outp, float scale, int epi)
{
  __shared__ alignas(16) u16 Lds[73728];   // 144 KiB
  const int tid = threadIdx.x;
  const int w = tid>>6, l = tid&63;
  const int l15 = l&15, lg = l>>4;
  const int wm = w&1, wn = (w>>1)&1, wk = w>>2;   // 2M x 2N x 2K
  const int row0 = blockIdx.y*128, col0 = blockIdx.x*256;
  constexpr int K = 2048;
  constexpr int NT = K/64;

  f32x4 acc[4][8];
  #pragma unroll
  for (int i=0;i<4;i++)
    #pragma unroll
    for (int j=0;j<8;j++)
      #pragma unroll
      for (int r=0;r<4;r++) acc[i][j][r] = 0.f;

  int sBrow[4], sBcol[4];
  #pragma unroll
  for (int p=0;p<4;p++){
    int s = p*512 + tid;
    sBrow[p] = s>>3;  sBcol[p] = ((s&7) ^ ((s>>3)&7))*8;
  }
  const int sArow0 = sBrow[0], sAcol0 = sBcol[0];
  const int sArow1 = sBrow[1], sAcol1 = sBcol[1];

  auto stageA = [&](int slot, int kt){
    gld16(A + (size_t)(row0 + sArow0)*K + kt*64 + sAcol0,
          &Lds[slot*8192 + (size_t)(w*64)*8]);
    gld16(A + (size_t)(row0 + sArow1)*K + kt*64 + sAcol1,
          &Lds[slot*8192 + (size_t)(512 + w*64)*8]);
  };
  auto stageB = [&](int slot, int kt){
    #pragma unroll
    for (int p=0;p<4;p++)
      gld16(W + (size_t)(col0 + sBrow[p])*K + kt*64 + sBcol[p],
            &Lds[24576 + slot*16384 + (size_t)(p*512 + w*64)*8]);
  };
  auto readA = [&](int slot, short8 (&af)[4]){
    #pragma unroll
    for (int i=0;i<4;i++){
      int r = wm*64 + i*16 + l15;
      int byt = slot*16384 + r*128 + (((wk*4+lg) ^ (r&7))<<4);
      af[i] = *reinterpret_cast<const short8*>((const char*)Lds + byt);
    }
  };
  auto readB = [&](int slot, short8 (&bf)[8]){
    #pragma unroll
    for (int j=0;j<8;j++){
      int r = wn*128 + j*16 + l15;
      int byt = 49152 + slot*32768 + r*128 + (((wk*4+lg) ^ (r&7))<<4);
      bf[j] = *reinterpret_cast<const short8*>((const char*)Lds + byt);
    }
  };

  stageA(0, 0); stageB(0, 0);
  stageA(1, 1); stageB(1, 1);
  SCHED0();
  asm volatile("s_waitcnt vmcnt(6)" ::: "memory");
  __builtin_amdgcn_s_barrier();
  SCHED0();

  int sl = 0;
  for (int t=0; t<NT; ++t){
    int st = sl+2; if (st>=3) st-=3;
    int tn = (t+2) & (NT-1);
    stageA(st, tn);
    stageB(st, tn);
    short8 af[4], bf[8];
    readA(sl, af);
    readB(sl, bf);
    #pragma unroll
    for (int i=0;i<4;i++)
      #pragma unroll
      for (int j=0;j<8;j++)
        acc[i][j] = __builtin_amdgcn_mfma_f32_16x16x32_bf16(af[i], bf[j], acc[i][j], 0, 0, 0);
    SCHED0();
    asm volatile("s_waitcnt vmcnt(6)" ::: "memory");
    __builtin_amdgcn_s_barrier();
    SCHED0();
    sl = sl+1; if (sl>=3) sl = 0;
  }

  __syncthreads();
  float* R = (float*)Lds;
  const int pair = wm*2 + wn;
  if (wk == 1){
    #pragma unroll
    for (int i=0;i<4;i++)
      #pragma unroll
      for (int j=0;j<8;j++)
        *reinterpret_cast<f32x4*>(&R[pair*8192 + (i*8+j)*256 + l*4]) = acc[i][j];
  }
  __syncthreads();
  if (wk == 0){
    #pragma unroll
    for (int i=0;i<4;i++)
      #pragma unroll
      for (int j=0;j<8;j++){
        f32x4 o = *reinterpret_cast<const f32x4*>(&R[pair*8192 + (i*8+j)*256 + l*4]);
        #pragma unroll
        for (int r=0;r<4;r++) acc[i][j][r] += o[r];
      }

    if (epi == 0){          // Q/K: bf16 scatter to [b][h][t][d]
      u16* O = (u16*)outp;
      #pragma unroll
      for (int i=0;i<4;i++)
        #pragma unroll
        for (int j=0;j<8;j++)
          #pragma unroll
          for (int r=0;r<4;r++){
            int m = row0 + wm*64 + i*16 + lg*4 + r;
            int n = col0 + wn*128 + j*16 + l15;
            int b = m >> 11, tt = m & 2047;
            int h = n >> 7,  d = n & 127;
            O[(((size_t)(b*16 + h)*2048 + tt)<<7) + d] = f2bf(acc[i][j][r] * scale);
          }
    } else if (epi == 2){   // V: bf16 V^T [b][h][d][t]
      u16* O = (u16*)outp;
      #pragma unroll
      for (int i=0;i<4;i++)
        #pragma unroll
        for (int j=0;j<8;j++){
          int m0 = row0 + wm*64 + i*16 + lg*4;
          int n  = col0 + wn*128 + j*16 + l15;
          int b = m0 >> 11, tt = m0 & 2047;
          int h = n >> 7,  d = n & 127;
          ushort4 u;
          u.x = f2bf(acc[i][j][0]); u.y = f2bf(acc[i][j][1]);
          u.z = f2bf(acc[i][j][2]); u.w = f2bf(acc[i][j][3]);
          *reinterpret_cast<ushort4*>(&O[(((size_t)(b*16 + h)<<7) + d)*2048 + tt]) = u;
        }
    } else {                // out-proj: f32 row-major [m][n]
      float* O = (float*)outp;
      #pragma unroll
      for (int i=0;i<4;i++)
        #pragma unroll
        for (int j=0;j<8;j++)
          #pragma unroll
          for (int r=0;r<4;r++){
            int m = row0 + wm*64 + i*16 + lg*4 + r;
            int n = col0 + wn*128 + j*16 + l15;
            O[(size_t)m*2048 + n] = acc[i][j][r];
          }
    }
  }
}

__global__ __launch_bounds__(512,2) void gemm_qkv(const u16* __restrict__ A,
    const u16* __restrict__ Wq, const u16* __restrict__ Wk, const u16* __restrict__ Wv,
    u16* __restrict__ qo, u16* __restrict__ ko, u16* __restrict__ vt, float qscale)
{
  const u16* W; void* O; float sc; int epi;
  if (blockIdx.z == 0){ W = Wq; O = qo; sc = qscale; epi = 0; }
  else if (blockIdx.z == 1){ W = Wk; O = ko; sc = 1.f; epi = 0; }
  else { W = Wv; O = vt; sc = 1.f; epi = 2; }
  gemm256_body(A, W, O, sc, epi);
}

__global__ __launch_bounds__(512,2) void gemm_out(const u16* __restrict__ A,
    const u16* __restrict__ W, float* __restrict__ O)
{
  gemm256_body(A, W, O, 1.f, 1);
}

// ---------------- flash attention, 32x32x16 MFMA, swapped QK^T -------------
// Round-10: 512-thread blocks (8 waves x 32 q-rows = 256 q/block), grid 256,
// 64KB dbuf LDS -> 2 blocks/CU = 16 waves/CU = 4 waves/SIMD (2x TLP).
// __launch_bounds__(512,4) caps VGPR at 128. Register diet: per-step split
// into two kv-32 halves — each half: QK^T(16 MFMA) -> per-half defer-max ->
// {exp/pack one pa -> 4 PV MFMA} x2. Online softmax at half granularity is
// the standard update (rescale applies to all prior accO/lrun). accS live
// = 16 regs, pa = 8 (one at a time).
__global__ __launch_bounds__(512,4) void attn_kernel(
    const u16* __restrict__ Q, const u16* __restrict__ Kg,
    const u16* __restrict__ Vt, u16* __restrict__ Y)
{
  __shared__ alignas(16) u16 Ks[2][64*128];
  __shared__ alignas(16) u16 Vs[2][64*128];
  const int tid = threadIdx.x;
  const int w = tid>>6, l = tid&63;
  const int l31 = l&31, hi = l>>5;
  // 256 blocks, XCD-chunked: 32 consecutive work-ids per XCD = 4 whole bh.
  const int swz = (blockIdx.x&7)*32 + (blockIdx.x>>3);
  const int bh = swz >> 3;
  const int q0 = (swz & 7) * 256;

  // Q B-frags: lane holds q = q0+w*32+l31, d = ds*16 + hi*8 .. +8 (16B)
  short8 qf[8];
  #pragma unroll
  for (int ds=0; ds<8; ds++)
    qf[ds] = *reinterpret_cast<const short8*>(
        Q + ((size_t)bh*2048 + q0 + w*32 + l31)*128 + ds*16 + hi*8);

  f32x16 accO[4];
  #pragma unroll
  for (int dt=0;dt<4;dt++)
    #pragma unroll
    for (int r=0;r<16;r++) accO[dt][r] = 0.f;
  float mrun = -1e30f, lrun = 0.f;   // per lane: q = l&31

  // staging maps (inverse-swizzled global source, linear LDS dest)
  // 1024 chunks over 512 threads: 2 K-chunks + 2 V-chunks per thread.
  int krow_[2], kcol_[2], vd_[2], vkv_[2];
  #pragma unroll
  for (int p=0;p<2;p++){
    int s = p*512 + tid;         // slot in [0,1024), 16B chunks
    int r = s>>4, c = s&15;
    int cu = c ^ (r&15);
    krow_[p] = r;  kcol_[p] = cu*8;               // K: row=kv (256B rows)
    vd_[p] = r*2 + (cu>>3);  vkv_[p] = (cu&7)*8;  // V: d-pair rows (256B)
  }

  auto stage = [&](int buf, int kvt){
    int kv0 = kvt*64;
    #pragma unroll
    for (int p=0;p<2;p++)
      gld16(Kg + ((size_t)bh*2048 + kv0 + krow_[p])*128 + kcol_[p],
            &Ks[buf][(size_t)(p*512 + w*64)*8]);
    #pragma unroll
    for (int p=0;p<2;p++)
      gld16(Vt + ((size_t)bh*128 + vd_[p])*2048 + kv0 + vkv_[p],
            &Vs[buf][(size_t)(p*512 + w*64)*8]);
  };

  stage(0, 0);
  __syncthreads();

  int cur = 0;
  for (int kvt=0; kvt<32; ++kvt){
    if (kvt+1 < 32) stage(cur^1, kvt+1);

    #pragma unroll
    for (int kt=0;kt<2;kt++){
      // ---- QK^T for kv-half kt: S^T = K Q^T, col=l31=q ----
      f32x16 accS;
      #pragma unroll
      for (int r=0;r<16;r++) accS[r] = 0.f;
      #pragma unroll
      for (int ds=0;ds<8;ds++){
        int row = kt*32 + l31;
        int byt = row*256 + (((ds*2 + hi) ^ (row&15))<<4);
        short8 kf = *reinterpret_cast<const short8*>((const char*)(&Ks[cur][0]) + byt);
        accS = __builtin_amdgcn_mfma_f32_32x32x16_bf16(kf, qf[ds], accS, 0, 0, 0);
      }

      // ---- per-half defer-max online softmax ----
      float pmax = accS[0];
      #pragma unroll
      for (int r=1;r<16;r++) pmax = fmaxf(pmax, accS[r]);
      pmax = fmaxf(pmax, __shfl_xor(pmax, 32, 64));
      if (__any(pmax > mrun + 8.f)){
        float mn = fmaxf(mrun, pmax);
        float c = __expf(mrun - mn);
        mrun = mn;
        lrun *= c;
        #pragma unroll
        for (int r=0;r<16;r++){
          int qrow = (r&3) + 8*(r>>2) + 4*hi;
          float cr = __shfl(c, qrow, 64);
          #pragma unroll
          for (int dt=0;dt<4;dt++) accO[dt][r] *= cr;
        }
      }

      // ---- exp/pack one pa at a time, each feeding 4 PV MFMAs ----
      float rs = 0.f;
      #pragma unroll
      for (int b=0;b<2;b++){
        float e0 = __expf(accS[b*8+0] - mrun);
        float e1 = __expf(accS[b*8+1] - mrun);
        float e2 = __expf(accS[b*8+2] - mrun);
        float e3 = __expf(accS[b*8+3] - mrun);
        float e4 = __expf(accS[b*8+4] - mrun);
        float e5 = __expf(accS[b*8+5] - mrun);
        float e6 = __expf(accS[b*8+6] - mrun);
        float e7 = __expf(accS[b*8+7] - mrun);
        rs += (e0+e1)+(e2+e3)+(e4+e5)+(e6+e7);
        u32 x01 = (u32)f2bf(e0) | ((u32)f2bf(e1)<<16);
        u32 x23 = (u32)f2bf(e2) | ((u32)f2bf(e3)<<16);
        u32 y01 = (u32)f2bf(e4) | ((u32)f2bf(e5)<<16);
        u32 y23 = (u32)f2bf(e6) | ((u32)f2bf(e7)<<16);
        u32 sx_x01 = __shfl_xor(x01, 32, 64);
        u32 sx_x23 = __shfl_xor(x23, 32, 64);
        u32 sx_y01 = __shfl_xor(y01, 32, 64);
        u32 sx_y23 = __shfl_xor(y23, 32, 64);
        int4 wv;
        wv.x = (int)(hi ? sx_y01 : x01);
        wv.y = (int)(hi ? sx_y23 : x23);
        wv.z = (int)(hi ? y01 : sx_x01);
        wv.w = (int)(hi ? y23 : sx_x23);
        short8 pa = *reinterpret_cast<short8*>(&wv);
        int ks = kt*2 + b;
        #pragma unroll
        for (int dt=0;dt<4;dt++){
          int d = dt*32 + l31;
          int cu = (d&1)*8 + ks*2 + hi;
          int byt = (d>>1)*256 + ((cu ^ ((d>>1)&15))<<4);
          short8 vf = *reinterpret_cast<const short8*>((const char*)(&Vs[cur][0]) + byt);
          accO[dt] = __builtin_amdgcn_mfma_f32_32x32x16_bf16(pa, vf, accO[dt], 0, 0, 0);
        }
      }
      rs += __shfl_xor(rs, 32, 64);
      lrun += rs;
    }

    __syncthreads();
    cur ^= 1;
  }

  // ---- epilogue: Y[b][t][h*128+d] ----
  const int b_ = bh >> 4, h_ = bh & 15;
  float inv = 1.f / lrun;
  #pragma unroll
  for (int r=0;r<16;r++){
    int qrow = (r&3) + 8*(r>>2) + 4*hi;
    float lr = __shfl(inv, qrow, 64);
    int t = q0 + w*32 + qrow;
    #pragma unroll
    for (int dt=0;dt<4;dt++){
      int d = dt*32 + l31;
      Y[((size_t)b_*2048 + t)*2048 + h_*128 + d] = f2bf(accO[dt][r] * lr);
    }
  }
}

// ---------------- launch ----------------
extern "C" void kernel_launch(void* const* d_in, const int* in_sizes, int n_in,
                              void* d_out, int out_size, void* d_ws, size_t ws_size,
                              hipStream_t stream)
{
  const float* x  = (const float*)d_in[0];
  const float* Wq = (const float*)d_in[1];
  const float* Wk = (const float*)d_in[2];
  const float* Wv = (const float*)d_in[3];
  const float* Wo = (const float*)d_in[4];
  float* out = (float*)d_out;
  char* ws = (char*)d_ws;

  const size_t MB = 1024*1024;
  u16* xb  = (u16*)(ws);            // 16 MiB bf16 x
  u16* wqb = (u16*)(ws + 16*MB);    //  8 MiB
  u16* wkb = (u16*)(ws + 24*MB);    //  8 MiB
  u16* wvb = (u16*)(ws + 32*MB);    //  8 MiB
  u16* wob = (u16*)(ws + 40*MB);    //  8 MiB
  u16* qb  = (u16*)(ws + 48*MB);    // 16 MiB [b][h][t][d]
  u16* kb  = (u16*)(ws + 64*MB);    // 16 MiB [b][h][t][d]
  u16* vtb = (u16*)(ws + 80*MB);    // 16 MiB [b][h][d][t]
  u16* yb  = wqb;                   // 16 MiB overlay: wq/wk dead after gemm_qkv

  cvt_kernel<<<2048, 256, 0, stream>>>(x, xb, 4096*2048);
  cvt4_kernel<<<dim3(1024,4), 256, 0, stream>>>(Wq, Wk, Wv, Wo,
                                                wqb, wkb, wvb, wob, 2048*2048);

  const float qscale = 0.08838834764831845f;  // 1/sqrt(128)
  gemm_qkv<<<dim3(8,32,3), 512, 0, stream>>>(xb, wqb, wkb, wvb, qb, kb, vtb, qscale);
  attn_kernel<<<256, 512, 0, stream>>>(qb, kb, vtb, yb);
  gemm_out<<<dim3(8,32), 512, 0, stream>>>(yb, wob, out);
}

// Round 11
// 282.272 us; speedup vs baseline: 1.4873x; 1.4873x over previous
//
#include <hip/hip_runtime.h>
#include <hip/hip_bf16.h>

typedef __attribute__((ext_vector_type(8))) short short8;
typedef __attribute__((ext_vector_type(4))) float f32x4;
typedef __attribute__((ext_vector_type(16))) float f32x16;
typedef unsigned short u16;
typedef unsigned int u32;

// B=2, T=2048, C=2048, H=16, HD=128; M = B*T = 4096, K = N = 2048
__device__ __forceinline__ u16 f2bf(float f){
  __hip_bfloat16 h = __float2bfloat16(f);
  return *reinterpret_cast<u16*>(&h);
}

__device__ __forceinline__ void gld16(const void* g, void* l){
  __builtin_amdgcn_global_load_lds((const __attribute__((address_space(1))) void*)g,
                                   (__attribute__((address_space(3))) void*)l, 16, 0, 0);
}

#define SCHED0() __builtin_amdgcn_sched_barrier(0)

// ---------------- f32 -> bf16 convert ----------------
__global__ __launch_bounds__(256) void cvt_kernel(const float* __restrict__ src,
                                                  u16* __restrict__ dst, int n){
  int i0 = (blockIdx.x*256 + threadIdx.x)*4;
  int stride = gridDim.x*256*4;
  for (int i = i0; i < n; i += stride){
    float4 f = *reinterpret_cast<const float4*>(src + i);
    ushort4 u;
    u.x = f2bf(f.x); u.y = f2bf(f.y); u.z = f2bf(f.z); u.w = f2bf(f.w);
    *reinterpret_cast<ushort4*>(dst + i) = u;
  }
}

// 4 weight matrices in one launch (blockIdx.y selects)
__global__ __launch_bounds__(256) void cvt4_kernel(
    const float* __restrict__ s0, const float* __restrict__ s1,
    const float* __restrict__ s2, const float* __restrict__ s3,
    u16* __restrict__ d0, u16* __restrict__ d1,
    u16* __restrict__ d2, u16* __restrict__ d3, int n){
  const float* s; u16* d;
  if (blockIdx.y == 0){ s = s0; d = d0; }
  else if (blockIdx.y == 1){ s = s1; d = d1; }
  else if (blockIdx.y == 2){ s = s2; d = d2; }
  else { s = s3; d = d3; }
  int i0 = (blockIdx.x*256 + threadIdx.x)*4;
  int stride = gridDim.x*256*4;
  for (int i = i0; i < n; i += stride){
    float4 f = *reinterpret_cast<const float4*>(s + i);
    ushort4 u;
    u.x = f2bf(f.x); u.y = f2bf(f.y); u.z = f2bf(f.z); u.w = f2bf(f.w);
    *reinterpret_cast<ushort4*>(d + i) = u;
  }
}

// ---------------- bf16 GEMM, 128x256 tile, BK=64, 8 waves (2Mx2Nx2K) -------
// (frozen from round 9)
__device__ __forceinline__ void gemm256_body(const u16* __restrict__ A,
    const u16* __restrict__ W, void* __restrict__ outp, float scale, int epi)
{
  __shared__ alignas(16) u16 Lds[73728];   // 144 KiB
  const int tid = threadIdx.x;
  const int w = tid>>6, l = tid&63;
  const int l15 = l&15, lg = l>>4;
  const int wm = w&1, wn = (w>>1)&1, wk = w>>2;   // 2M x 2N x 2K
  const int row0 = blockIdx.y*128, col0 = blockIdx.x*256;
  constexpr int K = 2048;
  constexpr int NT = K/64;

  f32x4 acc[4][8];
  #pragma unroll
  for (int i=0;i<4;i++)
    #pragma unroll
    for (int j=0;j<8;j++)
      #pragma unroll
      for (int r=0;r<4;r++) acc[i][j][r] = 0.f;

  int sBrow[4], sBcol[4];
  #pragma unroll
  for (int p=0;p<4;p++){
    int s = p*512 + tid;
    sBrow[p] = s>>3;  sBcol[p] = ((s&7) ^ ((s>>3)&7))*8;
  }
  const int sArow0 = sBrow[0], sAcol0 = sBcol[0];
  const int sArow1 = sBrow[1], sAcol1 = sBcol[1];

  auto stageA = [&](int slot, int kt){
    gld16(A + (size_t)(row0 + sArow0)*K + kt*64 + sAcol0,
          &Lds[slot*8192 + (size_t)(w*64)*8]);
    gld16(A + (size_t)(row0 + sArow1)*K + kt*64 + sAcol1,
          &Lds[slot*8192 + (size_t)(512 + w*64)*8]);
  };
  auto stageB = [&](int slot, int kt){
    #pragma unroll
    for (int p=0;p<4;p++)
      gld16(W + (size_t)(col0 + sBrow[p])*K + kt*64 + sBcol[p],
            &Lds[24576 + slot*16384 + (size_t)(p*512 + w*64)*8]);
  };
  auto readA = [&](int slot, short8 (&af)[4]){
    #pragma unroll
    for (int i=0;i<4;i++){
      int r = wm*64 + i*16 + l15;
      int byt = slot*16384 + r*128 + (((wk*4+lg) ^ (r&7))<<4);
      af[i] = *reinterpret_cast<const short8*>((const char*)Lds + byt);
    }
  };
  auto readB = [&](int slot, short8 (&bf)[8]){
    #pragma unroll
    for (int j=0;j<8;j++){
      int r = wn*128 + j*16 + l15;
      int byt = 49152 + slot*32768 + r*128 + (((wk*4+lg) ^ (r&7))<<4);
      bf[j] = *reinterpret_cast<const short8*>((const char*)Lds + byt);
    }
  };

  stageA(0, 0); stageB(0, 0);
  stageA(1, 1); stageB(1, 1);
  SCHED0();
  asm volatile("s_waitcnt vmcnt(6)" ::: "memory");
  __builtin_amdgcn_s_barrier();
  SCHED0();

  int sl = 0;
  for (int t=0; t<NT; ++t){
    int st = sl+2; if (st>=3) st-=3;
    int tn = (t+2) & (NT-1);
    stageA(st, tn);
    stageB(st, tn);
    short8 af[4], bf[8];
    readA(sl, af);
    readB(sl, bf);
    #pragma unroll
    for (int i=0;i<4;i++)
      #pragma unroll
      for (int j=0;j<8;j++)
        acc[i][j] = __builtin_amdgcn_mfma_f32_16x16x32_bf16(af[i], bf[j], acc[i][j], 0, 0, 0);
    SCHED0();
    asm volatile("s_waitcnt vmcnt(6)" ::: "memory");
    __builtin_amdgcn_s_barrier();
    SCHED0();
    sl = sl+1; if (sl>=3) sl = 0;
  }

  __syncthreads();
  float* R = (float*)Lds;
  const int pair = wm*2 + wn;
  if (wk == 1){
    #pragma unroll
    for (int i=0;i<4;i++)
      #pragma unroll
      for (int j=0;j<8;j++)
        *reinterpret_cast<f32x4*>(&R[pair*8192 + (i*8+j)*256 + l*4]) = acc[i][j];
  }
  __syncthreads();
  if (wk == 0){
    #pragma unroll
    for (int i=0;i<4;i++)
      #pragma unroll
      for (int j=0;j<8;j++){
        f32x4 o = *reinterpret_cast<const f32x4*>(&R[pair*8192 + (i*8+j)*256 + l*4]);
        #pragma unroll
        for (int r=0;r<4;r++) acc[i][j][r] += o[r];
      }

    if (epi == 0){          // Q/K: bf16 scatter to [b][h][t][d]
      u16* O = (u16*)outp;
      #pragma unroll
      for (int i=0;i<4;i++)
        #pragma unroll
        for (int j=0;j<8;j++)
          #pragma unroll
          for (int r=0;r<4;r++){
            int m = row0 + wm*64 + i*16 + lg*4 + r;
            int n = col0 + wn*128 + j*16 + l15;
            int b = m >> 11, tt = m & 2047;
            int h = n >> 7,  d = n & 127;
            O[(((size_t)(b*16 + h)*2048 + tt)<<7) + d] = f2bf(acc[i][j][r] * scale);
          }
    } else if (epi == 2){   // V: bf16 V^T [b][h][d][t]
      u16* O = (u16*)outp;
      #pragma unroll
      for (int i=0;i<4;i++)
        #pragma unroll
        for (int j=0;j<8;j++){
          int m0 = row0 + wm*64 + i*16 + lg*4;
          int n  = col0 + wn*128 + j*16 + l15;
          int b = m0 >> 11, tt = m0 & 2047;
          int h = n >> 7,  d = n & 127;
          ushort4 u;
          u.x = f2bf(acc[i][j][0]); u.y = f2bf(acc[i][j][1]);
          u.z = f2bf(acc[i][j][2]); u.w = f2bf(acc[i][j][3]);
          *reinterpret_cast<ushort4*>(&O[(((size_t)(b*16 + h)<<7) + d)*2048 + tt]) = u;
        }
    } else {                // out-proj: f32 row-major [m][n]
      float* O = (float*)outp;
      #pragma unroll
      for (int i=0;i<4;i++)
        #pragma unroll
        for (int j=0;j<8;j++)
          #pragma unroll
          for (int r=0;r<4;r++){
            int m = row0 + wm*64 + i*16 + lg*4 + r;
            int n = col0 + wn*128 + j*16 + l15;
            O[(size_t)m*2048 + n] = acc[i][j][r];
          }
    }
  }
}

__global__ __launch_bounds__(512,2) void gemm_qkv(const u16* __restrict__ A,
    const u16* __restrict__ Wq, const u16* __restrict__ Wk, const u16* __restrict__ Wv,
    u16* __restrict__ qo, u16* __restrict__ ko, u16* __restrict__ vt, float qscale)
{
  const u16* W; void* O; float sc; int epi;
  if (blockIdx.z == 0){ W = Wq; O = qo; sc = qscale; epi = 0; }
  else if (blockIdx.z == 1){ W = Wk; O = ko; sc = 1.f; epi = 0; }
  else { W = Wv; O = vt; sc = 1.f; epi = 2; }
  gemm256_body(A, W, O, sc, epi);
}

__global__ __launch_bounds__(512,2) void gemm_out(const u16* __restrict__ A,
    const u16* __restrict__ W, float* __restrict__ O)
{
  gemm256_body(A, W, O, 1.f, 1);
}

// ---------------- flash attention, 32x32x16 MFMA, swapped QK^T -------------
// Round-11: kv-split waves. 512 blocks x 512 thr (8 waves): wave (sub,kvh),
// sub = q-subblock (4 x 32q), kvh = kv-half of each staged 64-kv tile.
// Per wave-step: 8 QK MFMA + 8 PV MFMA over its 32 kv (accS live = 16).
// Total waves 4096 -> 16 waves/CU (2 blocks x 65KB LDS). Per-wave body =
// round-9 structure (VGPR=128 proven). Epilogue: kvh=1 writes accO/m/l to
// the dead K/V LDS (barrier-protected overlay); kvh=0 merges (standard
// m/l rescale) and writes Y. No launch_bounds register squeeze.
__global__ __launch_bounds__(512,2) void attn_kernel(
    const u16* __restrict__ Q, const u16* __restrict__ Kg,
    const u16* __restrict__ Vt, u16* __restrict__ Y)
{
  __shared__ alignas(16) u16 SMEM[32768];   // 64KB: K bufs @0, V bufs @16384 (u16 idx)
  __shared__ float ML[256];                  // [0:128) m, [128:256) l  (sub*32+q)
  const int tid = threadIdx.x;
  const int w = tid>>6, l = tid&63;
  const int l31 = l&31, hi = l>>5;
  const int sub = w&3, kvh = w>>2;
  // XCD-chunked bijective swizzle (512 blocks): 64 work-ids/XCD = 4 whole bh.
  const int swz = (blockIdx.x&7)*64 + (blockIdx.x>>3);
  const int bh = swz >> 4;
  const int q0 = (swz & 15) * 128;

  // Q B-frags: lane holds q = q0+sub*32+l31, d = ds*16 + hi*8 .. +8 (16B)
  short8 qf[8];
  #pragma unroll
  for (int ds=0; ds<8; ds++)
    qf[ds] = *reinterpret_cast<const short8*>(
        Q + ((size_t)bh*2048 + q0 + sub*32 + l31)*128 + ds*16 + hi*8);

  f32x16 accO[4];
  #pragma unroll
  for (int dt=0;dt<4;dt++)
    #pragma unroll
    for (int r=0;r<16;r++) accO[dt][r] = 0.f;
  float mrun = -1e30f, lrun = 0.f;   // per lane: q = l&31

  // staging maps: 2048 chunks over 512 thr = 4/thr (2 K + 2 V)
  int krow_[2], kcol_[2], vd_[2], vkv_[2];
  #pragma unroll
  for (int p=0;p<2;p++){
    int s = p*512 + tid;           // chunk in [0,1024)
    int r = s>>4, c = s&15;
    int cu = c ^ (r&15);
    krow_[p] = r;  kcol_[p] = cu*8;               // K: row=kv (256B rows)
    vd_[p] = r*2 + (cu>>3);  vkv_[p] = (cu&7)*8;  // V: d-pair rows (256B)
  }

  auto stage = [&](int buf, int kvt){
    int kv0 = kvt*64;
    #pragma unroll
    for (int p=0;p<2;p++)
      gld16(Kg + ((size_t)bh*2048 + kv0 + krow_[p])*128 + kcol_[p],
            &SMEM[buf*8192 + (size_t)(p*512 + w*64)*8]);
    #pragma unroll
    for (int p=0;p<2;p++)
      gld16(Vt + ((size_t)bh*128 + vd_[p])*2048 + kv0 + vkv_[p],
            &SMEM[16384 + buf*8192 + (size_t)(p*512 + w*64)*8]);
  };

  stage(0, 0);
  __syncthreads();

  int cur = 0;
  for (int kvt=0; kvt<32; ++kvt){
    if (kvt+1 < 32) stage(cur^1, kvt+1);

    // ---- QK^T over my kv-half: S^T = K Q^T, col = l31 = q ----
    f32x16 accS;
    #pragma unroll
    for (int r=0;r<16;r++) accS[r] = 0.f;
    #pragma unroll
    for (int ds=0;ds<8;ds++){
      int row = kvh*32 + l31;
      int byt = cur*16384 + row*256 + (((ds*2 + hi) ^ (row&15))<<4);
      short8 kf = *reinterpret_cast<const short8*>((const char*)SMEM + byt);
      accS = __builtin_amdgcn_mfma_f32_32x32x16_bf16(kf, qf[ds], accS, 0, 0, 0);
    }

    // ---- defer-max online softmax ----
    float pmax = accS[0];
    #pragma unroll
    for (int r=1;r<16;r++) pmax = fmaxf(pmax, accS[r]);
    pmax = fmaxf(pmax, __shfl_xor(pmax, 32, 64));
    if (__any(pmax > mrun + 8.f)){
      float mn = fmaxf(mrun, pmax);
      float c = __expf(mrun - mn);
      mrun = mn;
      lrun *= c;
      #pragma unroll
      for (int r=0;r<16;r++){
        int qrow = (r&3) + 8*(r>>2) + 4*hi;
        float cr = __shfl(c, qrow, 64);
        #pragma unroll
        for (int dt=0;dt<4;dt++) accO[dt][r] *= cr;
      }
    }

    // ---- exp/pack one pa at a time, each feeding 4 PV MFMAs ----
    float rs = 0.f;
    #pragma unroll
    for (int b=0;b<2;b++){
      float e0 = __expf(accS[b*8+0] - mrun);
      float e1 = __expf(accS[b*8+1] - mrun);
      float e2 = __expf(accS[b*8+2] - mrun);
      float e3 = __expf(accS[b*8+3] - mrun);
      float e4 = __expf(accS[b*8+4] - mrun);
      float e5 = __expf(accS[b*8+5] - mrun);
      float e6 = __expf(accS[b*8+6] - mrun);
      float e7 = __expf(accS[b*8+7] - mrun);
      rs += (e0+e1)+(e2+e3)+(e4+e5)+(e6+e7);
      u32 x01 = (u32)f2bf(e0) | ((u32)f2bf(e1)<<16);
      u32 x23 = (u32)f2bf(e2) | ((u32)f2bf(e3)<<16);
      u32 y01 = (u32)f2bf(e4) | ((u32)f2bf(e5)<<16);
      u32 y23 = (u32)f2bf(e6) | ((u32)f2bf(e7)<<16);
      u32 sx_x01 = __shfl_xor(x01, 32, 64);
      u32 sx_x23 = __shfl_xor(x23, 32, 64);
      u32 sx_y01 = __shfl_xor(y01, 32, 64);
      u32 sx_y23 = __shfl_xor(y23, 32, 64);
      int4 wv;
      wv.x = (int)(hi ? sx_y01 : x01);
      wv.y = (int)(hi ? sx_y23 : x23);
      wv.z = (int)(hi ? y01 : sx_x01);
      wv.w = (int)(hi ? y23 : sx_x23);
      short8 pa = *reinterpret_cast<short8*>(&wv);
      int ksg = kvh*2 + b;                       // kv quad within 64-tile
      #pragma unroll
      for (int dt=0;dt<4;dt++){
        int d = dt*32 + l31;
        int cu2 = (d&1)*8 + ksg*2 + hi;
        int byt = 32768 + cur*16384 + (d>>1)*256 + ((cu2 ^ ((d>>1)&15))<<4);
        short8 vf = *reinterpret_cast<const short8*>((const char*)SMEM + byt);
        accO[dt] = __builtin_amdgcn_mfma_f32_32x32x16_bf16(pa, vf, accO[dt], 0, 0, 0);
      }
    }
    rs += __shfl_xor(rs, 32, 64);
    lrun += rs;

    __syncthreads();
    cur ^= 1;
  }

  // ---- kv-half merge via LDS overlay (K/V buffers dead after last barrier) ----
  float* R = (float*)SMEM;                 // 16384 floats = 64KB
  if (kvh == 1){
    #pragma unroll
    for (int r=0;r<16;r++){
      int qrow = (r&3) + 8*(r>>2) + 4*hi;
      #pragma unroll
      for (int dt=0;dt<4;dt++)
        R[sub*4096 + qrow*128 + dt*32 + l31] = accO[dt][r];
    }
    if (!hi){ ML[sub*32 + l31] = mrun; ML[128 + sub*32 + l31] = lrun; }
  }
  __syncthreads();
  if (kvh == 0){
    float m1 = ML[sub*32 + l31], l1 = ML[128 + sub*32 + l31];
    float mm = fmaxf(mrun, m1);
    float s0 = __expf(mrun - mm), s1 = __expf(m1 - mm);
    float linv = 1.f / (lrun*s0 + l1*s1);
    const int b_ = bh >> 4, h_ = bh & 15;
    #pragma unroll
    for (int r=0;r<16;r++){
      int qrow = (r&3) + 8*(r>>2) + 4*hi;
      float s0q = __shfl(s0, qrow, 64);
      float s1q = __shfl(s1, qrow, 64);
      float liq = __shfl(linv, qrow, 64);
      int t = q0 + sub*32 + qrow;
      #pragma unroll
      for (int dt=0;dt<4;dt++){
        int d = dt*32 + l31;
        float o = accO[dt][r]*s0q + R[sub*4096 + qrow*128 + d]*s1q;
        Y[((size_t)b_*2048 + t)*2048 + h_*128 + d] = f2bf(o * liq);
      }
    }
  }
}

// ---------------- launch ----------------
extern "C" void kernel_launch(void* const* d_in, const int* in_sizes, int n_in,
                              void* d_out, int out_size, void* d_ws, size_t ws_size,
                              hipStream_t stream)
{
  const float* x  = (const float*)d_in[0];
  const float* Wq = (const float*)d_in[1];
  const float* Wk = (const float*)d_in[2];
  const float* Wv = (const float*)d_in[3];
  const float* Wo = (const float*)d_in[4];
  float* out = (float*)d_out;
  char* ws = (char*)d_ws;

  const size_t MB = 1024*1024;
  u16* xb  = (u16*)(ws);            // 16 MiB bf16 x
  u16* wqb = (u16*)(ws + 16*MB);    //  8 MiB
  u16* wkb = (u16*)(ws + 24*MB);    //  8 MiB
  u16* wvb = (u16*)(ws + 32*MB);    //  8 MiB
  u16* wob = (u16*)(ws + 40*MB);    //  8 MiB
  u16* qb  = (u16*)(ws + 48*MB);    // 16 MiB [b][h][t][d]
  u16* kb  = (u16*)(ws + 64*MB);    // 16 MiB [b][h][t][d]
  u16* vtb = (u16*)(ws + 80*MB);    // 16 MiB [b][h][d][t]
  u16* yb  = wqb;                   // 16 MiB overlay: wq/wk dead after gemm_qkv

  cvt_kernel<<<2048, 256, 0, stream>>>(x, xb, 4096*2048);
  cvt4_kernel<<<dim3(1024,4), 256, 0, stream>>>(Wq, Wk, Wv, Wo,
                                                wqb, wkb, wvb, wob, 2048*2048);

  const float qscale = 0.08838834764831845f;  // 1/sqrt(128)
  gemm_qkv<<<dim3(8,32,3), 512, 0, stream>>>(xb, wqb, wkb, wvb, qb, kb, vtb, qscale);
  attn_kernel<<<512, 512, 0, stream>>>(qb, kb, vtb, yb);
  gemm_out<<<dim3(8,32), 512, 0, stream>>>(yb, wob, out);
}

// Round 12
// 261.168 us; speedup vs baseline: 1.6075x; 1.0808x over previous
//
#include <hip/hip_runtime.h>
#include <hip/hip_bf16.h>

typedef __attribute__((ext_vector_type(8))) short short8;
typedef __attribute__((ext_vector_type(4))) float f32x4;
typedef __attribute__((ext_vector_type(16))) float f32x16;
typedef unsigned short u16;
typedef unsigned int u32;

// B=2, T=2048, C=2048, H=16, HD=128; M = B*T = 4096, K = N = 2048
__device__ __forceinline__ u16 f2bf(float f){
  __hip_bfloat16 h = __float2bfloat16(f);
  return *reinterpret_cast<u16*>(&h);
}

__device__ __forceinline__ void gld16(const void* g, void* l){
  __builtin_amdgcn_global_load_lds((const __attribute__((address_space(1))) void*)g,
                                   (__attribute__((address_space(3))) void*)l, 16, 0, 0);
}

#define SCHED0() __builtin_amdgcn_sched_barrier(0)

// ---------------- f32 -> bf16 convert ----------------
__global__ __launch_bounds__(256) void cvt_kernel(const float* __restrict__ src,
                                                  u16* __restrict__ dst, int n){
  int i0 = (blockIdx.x*256 + threadIdx.x)*4;
  int stride = gridDim.x*256*4;
  for (int i = i0; i < n; i += stride){
    float4 f = *reinterpret_cast<const float4*>(src + i);
    ushort4 u;
    u.x = f2bf(f.x); u.y = f2bf(f.y); u.z = f2bf(f.z); u.w = f2bf(f.w);
    *reinterpret_cast<ushort4*>(dst + i) = u;
  }
}

// 4 weight matrices in one launch (blockIdx.y selects)
__global__ __launch_bounds__(256) void cvt4_kernel(
    const float* __restrict__ s0, const float* __restrict__ s1,
    const float* __restrict__ s2, const float* __restrict__ s3,
    u16* __restrict__ d0, u16* __restrict__ d1,
    u16* __restrict__ d2, u16* __restrict__ d3, int n){
  const float* s; u16* d;
  if (blockIdx.y == 0){ s = s0; d = d0; }
  else if (blockIdx.y == 1){ s = s1; d = d1; }
  else if (blockIdx.y == 2){ s = s2; d = d2; }
  else { s = s3; d = d3; }
  int i0 = (blockIdx.x*256 + threadIdx.x)*4;
  int stride = gridDim.x*256*4;
  for (int i = i0; i < n; i += stride){
    float4 f = *reinterpret_cast<const float4*>(s + i);
    ushort4 u;
    u.x = f2bf(f.x); u.y = f2bf(f.y); u.z = f2bf(f.z); u.w = f2bf(f.w);
    *reinterpret_cast<ushort4*>(d + i) = u;
  }
}

// ---------------- bf16 GEMM, 128x256 tile, BK=64, 8 waves (2Mx2Nx2K) -------
// (frozen from round 9 — best measured: 115µs qkv, race-free)
__device__ __forceinline__ void gemm256_body(const u16* __restrict__ A,
    const u16* __restrict__ W, void* __restrict__ outp, float scale, int epi)
{
  __shared__ alignas(16) u16 Lds[73728];   // 144 KiB
  const int tid = threadIdx.x;
  const int w = tid>>6, l = tid&63;
  const int l15 = l&15, lg = l>>4;
  const int wm = w&1, wn = (w>>1)&1, wk = w>>2;   // 2M x 2N x 2K
  const int row0 = blockIdx.y*128, col0 = blockIdx.x*256;
  constexpr int K = 2048;
  constexpr int NT = K/64;

  f32x4 acc[4][8];
  #pragma unroll
  for (int i=0;i<4;i++)
    #pragma unroll
    for (int j=0;j<8;j++)
      #pragma unroll
      for (int r=0;r<4;r++) acc[i][j][r] = 0.f;

  int sBrow[4], sBcol[4];
  #pragma unroll
  for (int p=0;p<4;p++){
    int s = p*512 + tid;
    sBrow[p] = s>>3;  sBcol[p] = ((s&7) ^ ((s>>3)&7))*8;
  }
  const int sArow0 = sBrow[0], sAcol0 = sBcol[0];
  const int sArow1 = sBrow[1], sAcol1 = sBcol[1];

  auto stageA = [&](int slot, int kt){
    gld16(A + (size_t)(row0 + sArow0)*K + kt*64 + sAcol0,
          &Lds[slot*8192 + (size_t)(w*64)*8]);
    gld16(A + (size_t)(row0 + sArow1)*K + kt*64 + sAcol1,
          &Lds[slot*8192 + (size_t)(512 + w*64)*8]);
  };
  auto stageB = [&](int slot, int kt){
    #pragma unroll
    for (int p=0;p<4;p++)
      gld16(W + (size_t)(col0 + sBrow[p])*K + kt*64 + sBcol[p],
            &Lds[24576 + slot*16384 + (size_t)(p*512 + w*64)*8]);
  };
  auto readA = [&](int slot, short8 (&af)[4]){
    #pragma unroll
    for (int i=0;i<4;i++){
      int r = wm*64 + i*16 + l15;
      int byt = slot*16384 + r*128 + (((wk*4+lg) ^ (r&7))<<4);
      af[i] = *reinterpret_cast<const short8*>((const char*)Lds + byt);
    }
  };
  auto readB = [&](int slot, short8 (&bf)[8]){
    #pragma unroll
    for (int j=0;j<8;j++){
      int r = wn*128 + j*16 + l15;
      int byt = 49152 + slot*32768 + r*128 + (((wk*4+lg) ^ (r&7))<<4);
      bf[j] = *reinterpret_cast<const short8*>((const char*)Lds + byt);
    }
  };

  stageA(0, 0); stageB(0, 0);
  stageA(1, 1); stageB(1, 1);
  SCHED0();
  asm volatile("s_waitcnt vmcnt(6)" ::: "memory");
  __builtin_amdgcn_s_barrier();
  SCHED0();

  int sl = 0;
  for (int t=0; t<NT; ++t){
    int st = sl+2; if (st>=3) st-=3;
    int tn = (t+2) & (NT-1);
    stageA(st, tn);
    stageB(st, tn);
    short8 af[4], bf[8];
    readA(sl, af);
    readB(sl, bf);
    #pragma unroll
    for (int i=0;i<4;i++)
      #pragma unroll
      for (int j=0;j<8;j++)
        acc[i][j] = __builtin_amdgcn_mfma_f32_16x16x32_bf16(af[i], bf[j], acc[i][j], 0, 0, 0);
    SCHED0();
    asm volatile("s_waitcnt vmcnt(6)" ::: "memory");
    __builtin_amdgcn_s_barrier();
    SCHED0();
    sl = sl+1; if (sl>=3) sl = 0;
  }

  __syncthreads();
  float* R = (float*)Lds;
  const int pair = wm*2 + wn;
  if (wk == 1){
    #pragma unroll
    for (int i=0;i<4;i++)
      #pragma unroll
      for (int j=0;j<8;j++)
        *reinterpret_cast<f32x4*>(&R[pair*8192 + (i*8+j)*256 + l*4]) = acc[i][j];
  }
  __syncthreads();
  if (wk == 0){
    #pragma unroll
    for (int i=0;i<4;i++)
      #pragma unroll
      for (int j=0;j<8;j++){
        f32x4 o = *reinterpret_cast<const f32x4*>(&R[pair*8192 + (i*8+j)*256 + l*4]);
        #pragma unroll
        for (int r=0;r<4;r++) acc[i][j][r] += o[r];
      }

    if (epi == 0){          // Q/K: bf16 scatter to [b][h][t][d]
      u16* O = (u16*)outp;
      #pragma unroll
      for (int i=0;i<4;i++)
        #pragma unroll
        for (int j=0;j<8;j++)
          #pragma unroll
          for (int r=0;r<4;r++){
            int m = row0 + wm*64 + i*16 + lg*4 + r;
            int n = col0 + wn*128 + j*16 + l15;
            int b = m >> 11, tt = m & 2047;
            int h = n >> 7,  d = n & 127;
            O[(((size_t)(b*16 + h)*2048 + tt)<<7) + d] = f2bf(acc[i][j][r] * scale);
          }
    } else if (epi == 2){   // V: bf16 V^T [b][h][d][t]
      u16* O = (u16*)outp;
      #pragma unroll
      for (int i=0;i<4;i++)
        #pragma unroll
        for (int j=0;j<8;j++){
          int m0 = row0 + wm*64 + i*16 + lg*4;
          int n  = col0 + wn*128 + j*16 + l15;
          int b = m0 >> 11, tt = m0 & 2047;
          int h = n >> 7,  d = n & 127;
          ushort4 u;
          u.x = f2bf(acc[i][j][0]); u.y = f2bf(acc[i][j][1]);
          u.z = f2bf(acc[i][j][2]); u.w = f2bf(acc[i][j][3]);
          *reinterpret_cast<ushort4*>(&O[(((size_t)(b*16 + h)<<7) + d)*2048 + tt]) = u;
        }
    } else {                // out-proj: f32 row-major [m][n]
      float* O = (float*)outp;
      #pragma unroll
      for (int i=0;i<4;i++)
        #pragma unroll
        for (int j=0;j<8;j++)
          #pragma unroll
          for (int r=0;r<4;r++){
            int m = row0 + wm*64 + i*16 + lg*4 + r;
            int n = col0 + wn*128 + j*16 + l15;
            O[(size_t)m*2048 + n] = acc[i][j][r];
          }
    }
  }
}

__global__ __launch_bounds__(512,2) void gemm_qkv(const u16* __restrict__ A,
    const u16* __restrict__ Wq, const u16* __restrict__ Wk, const u16* __restrict__ Wv,
    u16* __restrict__ qo, u16* __restrict__ ko, u16* __restrict__ vt, float qscale)
{
  const u16* W; void* O; float sc; int epi;
  if (blockIdx.z == 0){ W = Wq; O = qo; sc = qscale; epi = 0; }
  else if (blockIdx.z == 1){ W = Wk; O = ko; sc = 1.f; epi = 0; }
  else { W = Wv; O = vt; sc = 1.f; epi = 2; }
  gemm256_body(A, W, O, sc, epi);
}

__global__ __launch_bounds__(512,2) void gemm_out(const u16* __restrict__ A,
    const u16* __restrict__ W, float* __restrict__ O)
{
  gemm256_body(A, W, O, 1.f, 1);
}

// ---------------- flash attention, 32x32x16 MFMA, swapped QK^T -------------
// Round-12: exact round-5 body (proven ~95-105µs in the 263µs config)
// + T5 s_setprio around QK and PV MFMA clusters (m191: +4-7% on attn).
// 512 blocks (XCD-chunked), 4 waves x 32 q-rows, KVBLK=64, 64KB dbuf LDS.
__global__ __launch_bounds__(256,2) void attn_kernel(
    const u16* __restrict__ Q, const u16* __restrict__ Kg,
    const u16* __restrict__ Vt, u16* __restrict__ Y)
{
  __shared__ alignas(16) u16 Ks[2][64*128];
  __shared__ alignas(16) u16 Vs[2][64*128];
  const int tid = threadIdx.x;
  const int w = tid>>6, l = tid&63;
  const int l31 = l&31, hi = l>>5;
  const int bh_swz = ((blockIdx.x&7)*64 + (blockIdx.x>>3));
  const int bh = bh_swz >> 4;
  const int q0 = (bh_swz & 15) * 128;

  short8 qf[8];
  #pragma unroll
  for (int ds=0; ds<8; ds++)
    qf[ds] = *reinterpret_cast<const short8*>(
        Q + ((size_t)bh*2048 + q0 + w*32 + l31)*128 + ds*16 + hi*8);

  f32x16 accO[4];
  #pragma unroll
  for (int dt=0;dt<4;dt++)
    #pragma unroll
    for (int r=0;r<16;r++) accO[dt][r] = 0.f;
  float mrun = -1e30f, lrun = 0.f;

  int krow_[4], kcol_[4], vd_[4], vkv_[4];
  #pragma unroll
  for (int p=0;p<4;p++){
    int s = p*256 + tid;
    int r = s>>4, c = s&15;
    int cu = c ^ (r&15);
    krow_[p] = r;  kcol_[p] = cu*8;
    vd_[p] = r*2 + (cu>>3);  vkv_[p] = (cu&7)*8;
  }

  auto stage = [&](int buf, int kvt){
    int kv0 = kvt*64;
    #pragma unroll
    for (int p=0;p<4;p++)
      gld16(Kg + ((size_t)bh*2048 + kv0 + krow_[p])*128 + kcol_[p],
            &Ks[buf][(size_t)(p*256 + w*64)*8]);
    #pragma unroll
    for (int p=0;p<4;p++)
      gld16(Vt + ((size_t)bh*128 + vd_[p])*2048 + kv0 + vkv_[p],
            &Vs[buf][(size_t)(p*256 + w*64)*8]);
  };

  stage(0, 0);
  __syncthreads();

  int cur = 0;
  for (int kvt=0; kvt<32; ++kvt){
    if (kvt+1 < 32) stage(cur^1, kvt+1);

    f32x16 accS[2];
    #pragma unroll
    for (int kt=0;kt<2;kt++)
      #pragma unroll
      for (int r=0;r<16;r++) accS[kt][r] = 0.f;
    __builtin_amdgcn_s_setprio(1);
    #pragma unroll
    for (int kt=0;kt<2;kt++){
      #pragma unroll
      for (int ds=0;ds<8;ds++){
        int row = kt*32 + l31;
        int byt = row*256 + (((ds*2 + hi) ^ (row&15))<<4);
        short8 kf = *reinterpret_cast<const short8*>((const char*)(&Ks[cur][0]) + byt);
        accS[kt] = __builtin_amdgcn_mfma_f32_32x32x16_bf16(kf, qf[ds], accS[kt], 0, 0, 0);
      }
    }
    __builtin_amdgcn_s_setprio(0);

    float pmax = accS[0][0];
    #pragma unroll
    for (int kt=0;kt<2;kt++)
      #pragma unroll
      for (int r=0;r<16;r++) pmax = fmaxf(pmax, accS[kt][r]);
    pmax = fmaxf(pmax, __shfl_xor(pmax, 32, 64));
    if (__any(pmax > mrun + 8.f)){
      float mn = fmaxf(mrun, pmax);
      float c = __expf(mrun - mn);
      mrun = mn;
      lrun *= c;
      #pragma unroll
      for (int r=0;r<16;r++){
        int qrow = (r&3) + 8*(r>>2) + 4*hi;
        float cr = __shfl(c, qrow, 64);
        #pragma unroll
        for (int dt=0;dt<4;dt++) accO[dt][r] *= cr;
      }
    }

    float rs = 0.f;
    short8 pa[4];
    #pragma unroll
    for (int kt=0;kt<2;kt++){
      #pragma unroll
      for (int b=0;b<2;b++){
        float e0 = __expf(accS[kt][b*8+0] - mrun);
        float e1 = __expf(accS[kt][b*8+1] - mrun);
        float e2 = __expf(accS[kt][b*8+2] - mrun);
        float e3 = __expf(accS[kt][b*8+3] - mrun);
        float e4 = __expf(accS[kt][b*8+4] - mrun);
        float e5 = __expf(accS[kt][b*8+5] - mrun);
        float e6 = __expf(accS[kt][b*8+6] - mrun);
        float e7 = __expf(accS[kt][b*8+7] - mrun);
        rs += (e0+e1)+(e2+e3)+(e4+e5)+(e6+e7);
        u32 x01 = (u32)f2bf(e0) | ((u32)f2bf(e1)<<16);
        u32 x23 = (u32)f2bf(e2) | ((u32)f2bf(e3)<<16);
        u32 y01 = (u32)f2bf(e4) | ((u32)f2bf(e5)<<16);
        u32 y23 = (u32)f2bf(e6) | ((u32)f2bf(e7)<<16);
        u32 sx_x01 = __shfl_xor(x01, 32, 64);
        u32 sx_x23 = __shfl_xor(x23, 32, 64);
        u32 sx_y01 = __shfl_xor(y01, 32, 64);
        u32 sx_y23 = __shfl_xor(y23, 32, 64);
        int4 wv;
        wv.x = (int)(hi ? sx_y01 : x01);
        wv.y = (int)(hi ? sx_y23 : x23);
        wv.z = (int)(hi ? y01 : sx_x01);
        wv.w = (int)(hi ? y23 : sx_x23);
        pa[kt*2+b] = *reinterpret_cast<short8*>(&wv);
      }
    }
    rs += __shfl_xor(rs, 32, 64);
    lrun += rs;

    __builtin_amdgcn_s_setprio(1);
    #pragma unroll
    for (int dt=0;dt<4;dt++){
      #pragma unroll
      for (int ks=0;ks<4;ks++){
        int d = dt*32 + l31;
        int cu = (d&1)*8 + ks*2 + hi;
        int byt = (d>>1)*256 + ((cu ^ ((d>>1)&15))<<4);
        short8 vf = *reinterpret_cast<const short8*>((const char*)(&Vs[cur][0]) + byt);
        accO[dt] = __builtin_amdgcn_mfma_f32_32x32x16_bf16(pa[ks], vf, accO[dt], 0, 0, 0);
      }
    }
    __builtin_amdgcn_s_setprio(0);

    __syncthreads();
    cur ^= 1;
  }

  const int b_ = bh >> 4, h_ = bh & 15;
  float inv = 1.f / lrun;
  #pragma unroll
  for (int r=0;r<16;r++){
    int qrow = (r&3) + 8*(r>>2) + 4*hi;
    float lr = __shfl(inv, qrow, 64);
    int t = q0 + w*32 + qrow;
    #pragma unroll
    for (int dt=0;dt<4;dt++){
      int d = dt*32 + l31;
      Y[((size_t)b_*2048 + t)*2048 + h_*128 + d] = f2bf(accO[dt][r] * lr);
    }
  }
}

// ---------------- launch ----------------
extern "C" void kernel_launch(void* const* d_in, const int* in_sizes, int n_in,
                              void* d_out, int out_size, void* d_ws, size_t ws_size,
                              hipStream_t stream)
{
  const float* x  = (const float*)d_in[0];
  const float* Wq = (const float*)d_in[1];
  const float* Wk = (const float*)d_in[2];
  const float* Wv = (const float*)d_in[3];
  const float* Wo = (const float*)d_in[4];
  float* out = (float*)d_out;
  char* ws = (char*)d_ws;

  const size_t MB = 1024*1024;
  u16* xb  = (u16*)(ws);            // 16 MiB bf16 x
  u16* wqb = (u16*)(ws + 16*MB);    //  8 MiB
  u16* wkb = (u16*)(ws + 24*MB);    //  8 MiB
  u16* wvb = (u16*)(ws + 32*MB);    //  8 MiB
  u16* wob = (u16*)(ws + 40*MB);    //  8 MiB
  u16* qb  = (u16*)(ws + 48*MB);    // 16 MiB [b][h][t][d]
  u16* kb  = (u16*)(ws + 64*MB);    // 16 MiB [b][h][t][d]
  u16* vtb = (u16*)(ws + 80*MB);    // 16 MiB [b][h][d][t]
  u16* yb  = wqb;                   // 16 MiB overlay: wq/wk dead after gemm_qkv

  cvt_kernel<<<2048, 256, 0, stream>>>(x, xb, 4096*2048);
  cvt4_kernel<<<dim3(1024,4), 256, 0, stream>>>(Wq, Wk, Wv, Wo,
                                                wqb, wkb, wvb, wob, 2048*2048);

  const float qscale = 0.08838834764831845f;  // 1/sqrt(128)
  gemm_qkv<<<dim3(8,32,3), 512, 0, stream>>>(xb, wqb, wkb, wvb, qb, kb, vtb, qscale);
  attn_kernel<<<512, 256, 0, stream>>>(qb, kb, vtb, yb);
  gemm_out<<<dim3(8,32), 512, 0, stream>>>(yb, wob, out);
}